// Round 3
// baseline (686.348 us; speedup 1.0000x reference)
//
#include <hip/hip_runtime.h>
#include <cstdint>
#include <cstddef>

#define DEV static __device__ __forceinline__

constexpr int TT   = 8192;   // B*S tokens
constexpr int DD   = 1024;   // d_model
constexpr int DFF  = 512;
constexpr int NE   = 16;
constexpr int FDFF = 1024;   // fused shared dff
constexpr int NSLOT = TT * 2;                 // token-expert pairs
constexpr int NSLOT_PAD = NSLOT + NE * 128;   // padded to 128-row tiles
constexpr int MAXT = NSLOT / 128 + NE;        // 144 max live m-tiles

// ---- workspace layout (bytes) ----
constexpr size_t XB_OFF   = 0;                                    // x bf16 [T,D]
constexpr size_t HS_OFF   = XB_OFF  + (size_t)TT * DD * 2;        // shared hidden bf16 [T,FDFF]
constexpr size_t HR_OFF   = HS_OFF  + (size_t)TT * FDFF * 2;      // routed hidden bf16 [NSLOT_PAD,DFF]
constexpr size_t W1B_OFF  = HR_OFF  + (size_t)NSLOT_PAD * DFF * 2;
constexpr size_t W3B_OFF  = W1B_OFF + (size_t)NE * DFF * DD * 2;
constexpr size_t W2B_OFF  = W3B_OFF + (size_t)NE * DFF * DD * 2;
constexpr size_t SW1B_OFF = W2B_OFF + (size_t)NE * DD * DFF * 2;
constexpr size_t SW3B_OFF = SW1B_OFF + (size_t)FDFF * DD * 2;
constexpr size_t SW2B_OFF = SW3B_OFF + (size_t)FDFF * DD * 2;
constexpr size_t TKI_OFF  = SW2B_OFF + (size_t)DD * FDFF * 2;
constexpr size_t TKW_OFF  = TKI_OFF + (size_t)NSLOT * 4;
constexpr size_t STOK_OFF = TKW_OFF + (size_t)NSLOT * 4;
constexpr size_t SWT_OFF  = STOK_OFF + (size_t)NSLOT_PAD * 4;
constexpr size_t CNT_OFF  = SWT_OFF + (size_t)NSLOT_PAD * 4;
constexpr size_t CUR_OFF  = CNT_OFF + 64;
constexpr size_t OFS_OFF  = CUR_OFF + 64;
constexpr size_t TEX_OFF  = OFS_OFF + 128;
constexpr size_t TM0_OFF  = TEX_OFF + (size_t)MAXT * 4;

typedef __bf16 bf16x8 __attribute__((ext_vector_type(8)));
typedef float  floatx4 __attribute__((ext_vector_type(4)));
typedef unsigned short u16t;

DEV unsigned f2bf2(float lo, float hi) {
    unsigned a = __builtin_bit_cast(unsigned, lo);
    unsigned b = __builtin_bit_cast(unsigned, hi);
    a += 0x7FFFu + ((a >> 16) & 1u);
    b += 0x7FFFu + ((b >> 16) & 1u);
    return (a >> 16) | (b & 0xFFFF0000u);
}
DEV u16t f2bf1(float f) {
    unsigned u = __builtin_bit_cast(unsigned, f);
    u += 0x7FFFu + ((u >> 16) & 1u);
    return (u16t)(u >> 16);
}
DEV uint4 pack8(float4 a, float4 b) {
    uint4 r;
    r.x = f2bf2(a.x, a.y); r.y = f2bf2(a.z, a.w);
    r.z = f2bf2(b.x, b.y); r.w = f2bf2(b.z, b.w);
    return r;
}
DEV floatx4 mfma16(bf16x8 a, bf16x8 b, floatx4 c) {
    return __builtin_amdgcn_mfma_f32_16x16x32_bf16(a, b, c, 0, 0, 0);
}
DEV void glds16(const u16t* g, u16t* l) {   // async global->LDS, 16B/lane
    __builtin_amdgcn_global_load_lds(
        (const __attribute__((address_space(1))) unsigned int*)g,
        (__attribute__((address_space(3))) unsigned int*)l, 16, 0, 0);
}
DEV float dot4(float4 a, float4 b) { return a.x*b.x + a.y*b.y + a.z*b.z + a.w*b.w; }

// ---------------- weight fp32 -> bf16 pre-convert ----------------
__global__ __launch_bounds__(256) void k_cvtw(
        const float* __restrict__ w1, const float* __restrict__ w3, const float* __restrict__ w2,
        const float* __restrict__ sw1, const float* __restrict__ sw3, const float* __restrict__ sw2,
        u16t* __restrict__ w1b, u16t* __restrict__ w3b, u16t* __restrict__ w2b,
        u16t* __restrict__ sw1b, u16t* __restrict__ sw3b, u16t* __restrict__ sw2b) {
    int b = blockIdx.x;
    const float* src; u16t* dst; size_t base;
    if      (b < 4096)  { src = w1;  dst = w1b;  base = (size_t)b * 2048; }
    else if (b < 8192)  { src = w3;  dst = w3b;  base = (size_t)(b - 4096) * 2048; }
    else if (b < 12288) { src = w2;  dst = w2b;  base = (size_t)(b - 8192) * 2048; }
    else if (b < 12800) { src = sw1; dst = sw1b; base = (size_t)(b - 12288) * 2048; }
    else if (b < 13312) { src = sw3; dst = sw3b; base = (size_t)(b - 12800) * 2048; }
    else                { src = sw2; dst = sw2b; base = (size_t)(b - 13312) * 2048; }
    size_t i = base + (size_t)threadIdx.x * 8;
    float4 a = *(const float4*)(src + i);
    float4 c = *(const float4*)(src + i + 4);
    *(uint4*)(dst + i) = pack8(a, c);
}

// ---------------- x -> bf16 ----------------
__global__ __launch_bounds__(256) void k_cvtx(const float* __restrict__ x, u16t* __restrict__ xb) {
    size_t i = ((size_t)blockIdx.x * 256 + threadIdx.x) * 8;
    float4 a = *(const float4*)(x + i);
    float4 b = *(const float4*)(x + i + 4);
    *(uint4*)(xb + i) = pack8(a, b);
}

// ---------------- gate: no LDS, no dynamic reg indexing ----------------
__global__ __launch_bounds__(256) void k_gate(const float* __restrict__ x,
                                              const float* __restrict__ gw,
                                              const float* __restrict__ eb,
                                              int* __restrict__ tki, float* __restrict__ tkw,
                                              int* __restrict__ counts) {
    const int tid = threadIdx.x;
    const int wave = tid >> 6, lane = tid & 63;
    const int tok0 = blockIdx.x * 16 + wave * 4;
    float acc[4][16];
#pragma unroll
    for (int t = 0; t < 4; t++)
#pragma unroll
        for (int e = 0; e < 16; e++) acc[t][e] = 0.f;
#pragma unroll
    for (int i = 0; i < 4; i++) {
        const int d = i * 256 + lane * 4;
        float4 xv[4];
#pragma unroll
        for (int t = 0; t < 4; t++) xv[t] = *(const float4*)(x + (size_t)(tok0 + t) * DD + d);
#pragma unroll
        for (int e = 0; e < 16; e++) {
            float4 wv = *(const float4*)(gw + (size_t)e * DD + d);
#pragma unroll
            for (int t = 0; t < 4; t++) acc[t][e] += dot4(xv[t], wv);
        }
    }
#pragma unroll
    for (int t = 0; t < 4; t++)
#pragma unroll
        for (int e = 0; e < 16; e++) {
            float v = acc[t][e];
            v += __shfl_xor(v, 1);  v += __shfl_xor(v, 2);  v += __shfl_xor(v, 4);
            v += __shfl_xor(v, 8);  v += __shfl_xor(v, 16); v += __shfl_xor(v, 32);
            acc[t][e] = v;
        }
    if (lane == 0) {
        float ebs[16];
#pragma unroll
        for (int e = 0; e < 16; e++) ebs[e] = eb[e];
#pragma unroll
        for (int t = 0; t < 4; t++) {
            // track raw logits l0/l1 in scalars -- NO dynamic indexing into acc
            float b0 = -1e30f, b1v = -1e30f, l0 = 0.f, l1 = 0.f;
            int i0 = 0, i1 = 0;
#pragma unroll
            for (int e = 0; e < 16; e++) {
                float lv = acc[t][e];
                float bl = lv + ebs[e];
                if (bl > b0)       { b1v = b0; i1 = i0; l1 = l0; b0 = bl; i0 = e; l0 = lv; }
                else if (bl > b1v) { b1v = bl; i1 = e; l1 = lv; }
            }
            float s0 = 1.f / (1.f + expf(-l0));
            float s1 = 1.f / (1.f + expf(-l1));
            float dn = s0 + s1 + 1e-10f;
            int tok = tok0 + t;
            tki[tok * 2] = i0; tki[tok * 2 + 1] = i1;
            tkw[tok * 2] = s0 / dn; tkw[tok * 2 + 1] = s1 / dn;
            atomicAdd(&counts[i0], 1); atomicAdd(&counts[i1], 1);
        }
    }
}

// ---------------- scan: 128-padded offsets + tile map ----------------
__global__ void k_scan(const int* __restrict__ counts, int* __restrict__ offs,
                       int* __restrict__ texp, int* __restrict__ tm0) {
    if (threadIdx.x == 0) {
        int off = 0, t = 0;
        for (int e = 0; e < NE; e++) {
            offs[e] = off;
            int nt = (counts[e] + 127) >> 7;
            for (int i = 0; i < nt; i++) { texp[t] = e; tm0[t] = off + i * 128; t++; }
            off += nt * 128;
        }
        offs[NE] = off;
        for (; t < MAXT; t++) texp[t] = -1;
    }
}

// ---------------- scatter ----------------
__global__ __launch_bounds__(256) void k_scatter(const int* __restrict__ tki,
                                                 const float* __restrict__ tkw,
                                                 const int* __restrict__ offs,
                                                 int* __restrict__ cur,
                                                 int* __restrict__ stok, float* __restrict__ swt) {
    int idx = blockIdx.x * 256 + threadIdx.x;
    int tok = idx >> 1;
    int e = tki[idx];
    float w = tkw[idx];
    int pos = atomicAdd(&cur[e], 1);
    int slot = offs[e] + pos;
    stok[slot] = tok; swt[slot] = w;
}

// ---------------- shared GEMM1 (dual 128x64): Hs = swiglu ----------------
__global__ __launch_bounds__(256) void k_sgemm1(const u16t* __restrict__ xb,
        const u16t* __restrict__ w1b, const float* __restrict__ sb1,
        const u16t* __restrict__ w3b, const float* __restrict__ sb3,
        u16t* __restrict__ Hs) {
    __shared__ u16t As[128 * 32], B1s[64 * 32], B3s[64 * 32];
    const int m0 = blockIdx.x * 128, n0 = blockIdx.y * 64;
    const int tid = threadIdx.x, lane = tid & 63, wid = tid >> 6;
    const int wm = (wid & 1) * 64, wn = (wid >> 1) * 32;
    const int q = lane >> 4, r = lane & 15;
    const int srow = tid >> 2, scg = (tid & 3) * 8;
    floatx4 acc1[4][2], acc3[4][2];
#pragma unroll
    for (int i = 0; i < 4; i++)
#pragma unroll
        for (int j = 0; j < 2; j++) { acc1[i][j] = (floatx4)0.f; acc3[i][j] = (floatx4)0.f; }
    const u16t* a0  = xb  + (size_t)(m0 + srow) * DD + scg;
    const u16t* a1  = xb  + (size_t)(m0 + 64 + srow) * DD + scg;
    const u16t* b1g = w1b + (size_t)(n0 + srow) * DD + scg;
    const u16t* b3g = w3b + (size_t)(n0 + srow) * DD + scg;
    u16t* lA0 = As + tid * 8;
    u16t* lA1 = As + 2048 + tid * 8;
    u16t* lB1 = B1s + tid * 8;
    u16t* lB3 = B3s + tid * 8;
    for (int k0 = 0; k0 < DD; k0 += 32) {
        glds16(a0 + k0, lA0); glds16(a1 + k0, lA1);
        glds16(b1g + k0, lB1); glds16(b3g + k0, lB3);
        __syncthreads();
        bf16x8 af[4], f1[2], f3[2];
#pragma unroll
        for (int i = 0; i < 4; i++) af[i] = *(const bf16x8*)&As[(wm + i * 16 + r) * 32 + q * 8];
#pragma unroll
        for (int j = 0; j < 2; j++) {
            f1[j] = *(const bf16x8*)&B1s[(wn + j * 16 + r) * 32 + q * 8];
            f3[j] = *(const bf16x8*)&B3s[(wn + j * 16 + r) * 32 + q * 8];
        }
#pragma unroll
        for (int i = 0; i < 4; i++)
#pragma unroll
            for (int j = 0; j < 2; j++) {
                acc1[i][j] = mfma16(af[i], f1[j], acc1[i][j]);
                acc3[i][j] = mfma16(af[i], f3[j], acc3[i][j]);
            }
        __syncthreads();
    }
    float s1v[2], s3v[2];
#pragma unroll
    for (int j = 0; j < 2; j++) {
        int col = n0 + wn + j * 16 + r;
        s1v[j] = sb1[col]; s3v[j] = sb3[col];
    }
#pragma unroll
    for (int i = 0; i < 4; i++)
#pragma unroll
        for (int j = 0; j < 2; j++)
#pragma unroll
            for (int g = 0; g < 4; g++) {
                int row = m0 + wm + i * 16 + q * 4 + g;
                int col = n0 + wn + j * 16 + r;
                float z1 = acc1[i][j][g] + s1v[j];
                float z3 = acc3[i][j][g] + s3v[j];
                float h = (z1 / (1.f + __expf(-z1))) * z3;
                Hs[(size_t)row * FDFF + col] = f2bf1(h);
            }
}

// ---------------- shared GEMM2 (128x128): out = Hs@sw2^T + sb2 ----------------
__global__ __launch_bounds__(256) void k_sgemm2(const u16t* __restrict__ Hs,
        const u16t* __restrict__ sw2b, const float* __restrict__ sb2,
        float* __restrict__ out) {
    __shared__ u16t As[128 * 32], Bs[128 * 32];
    const int m0 = blockIdx.x * 128, n0 = blockIdx.y * 128;
    const int tid = threadIdx.x, lane = tid & 63, wid = tid >> 6;
    const int wm = (wid & 1) * 64, wn = (wid >> 1) * 64;
    const int q = lane >> 4, r = lane & 15;
    const int srow = tid >> 2, scg = (tid & 3) * 8;
    floatx4 acc[4][4];
#pragma unroll
    for (int i = 0; i < 4; i++)
#pragma unroll
        for (int j = 0; j < 4; j++) acc[i][j] = (floatx4)0.f;
    const u16t* a0 = Hs + (size_t)(m0 + srow) * FDFF + scg;
    const u16t* a1 = Hs + (size_t)(m0 + 64 + srow) * FDFF + scg;
    const u16t* b0 = sw2b + (size_t)(n0 + srow) * FDFF + scg;
    const u16t* b1 = sw2b + (size_t)(n0 + 64 + srow) * FDFF + scg;
    u16t* lA0 = As + tid * 8;       u16t* lA1 = As + 2048 + tid * 8;
    u16t* lB0 = Bs + tid * 8;       u16t* lB1 = Bs + 2048 + tid * 8;
    for (int k0 = 0; k0 < FDFF; k0 += 32) {
        glds16(a0 + k0, lA0); glds16(a1 + k0, lA1);
        glds16(b0 + k0, lB0); glds16(b1 + k0, lB1);
        __syncthreads();
        bf16x8 af[4], bf[4];
#pragma unroll
        for (int i = 0; i < 4; i++) af[i] = *(const bf16x8*)&As[(wm + i * 16 + r) * 32 + q * 8];
#pragma unroll
        for (int j = 0; j < 4; j++) bf[j] = *(const bf16x8*)&Bs[(wn + j * 16 + r) * 32 + q * 8];
#pragma unroll
        for (int i = 0; i < 4; i++)
#pragma unroll
            for (int j = 0; j < 4; j++) acc[i][j] = mfma16(af[i], bf[j], acc[i][j]);
        __syncthreads();
    }
    float bv[4];
#pragma unroll
    for (int j = 0; j < 4; j++) bv[j] = sb2[n0 + wn + j * 16 + r];
#pragma unroll
    for (int i = 0; i < 4; i++)
#pragma unroll
        for (int j = 0; j < 4; j++)
#pragma unroll
            for (int g = 0; g < 4; g++) {
                int row = m0 + wm + i * 16 + q * 4 + g;
                int col = n0 + wn + j * 16 + r;
                out[(size_t)row * DD + col] = acc[i][j][g] + bv[j];
            }
}

// ---------------- routed GEMM1 (dual 128x64, gathered) ----------------
__global__ __launch_bounds__(256) void k_rgemm1(const u16t* __restrict__ xb,
        const u16t* __restrict__ w1b, const float* __restrict__ b1,
        const u16t* __restrict__ w3b, const float* __restrict__ b3,
        const int* __restrict__ stok,
        const int* __restrict__ texp, const int* __restrict__ tm0,
        u16t* __restrict__ Hr) {
    const int te = texp[blockIdx.x];
    if (te < 0) return;
    const int m0 = tm0[blockIdx.x], n0 = blockIdx.y * 64;
    __shared__ u16t As[128 * 32], B1s[64 * 32], B3s[64 * 32];
    __shared__ int toksS[128];
    const int tid = threadIdx.x, lane = tid & 63, wid = tid >> 6;
    const int wm = (wid & 1) * 64, wn = (wid >> 1) * 32;
    const int q = lane >> 4, r = lane & 15;
    const int srow = tid >> 2, scg = (tid & 3) * 8;
    if (tid < 128) { int t = stok[m0 + tid]; toksS[tid] = t < 0 ? 0 : t; }
    __syncthreads();
    floatx4 acc1[4][2], acc3[4][2];
#pragma unroll
    for (int i = 0; i < 4; i++)
#pragma unroll
        for (int j = 0; j < 2; j++) { acc1[i][j] = (floatx4)0.f; acc3[i][j] = (floatx4)0.f; }
    const u16t* a0  = xb + (size_t)toksS[srow] * DD + scg;
    const u16t* a1  = xb + (size_t)toksS[64 + srow] * DD + scg;
    const u16t* b1g = w1b + (size_t)te * DFF * DD + (size_t)(n0 + srow) * DD + scg;
    const u16t* b3g = w3b + (size_t)te * DFF * DD + (size_t)(n0 + srow) * DD + scg;
    const float* b1e = b1 + (size_t)te * DFF;
    const float* b3e = b3 + (size_t)te * DFF;
    u16t* lA0 = As + tid * 8;
    u16t* lA1 = As + 2048 + tid * 8;
    u16t* lB1 = B1s + tid * 8;
    u16t* lB3 = B3s + tid * 8;
    for (int k0 = 0; k0 < DD; k0 += 32) {
        glds16(a0 + k0, lA0); glds16(a1 + k0, lA1);
        glds16(b1g + k0, lB1); glds16(b3g + k0, lB3);
        __syncthreads();
        bf16x8 af[4], f1[2], f3[2];
#pragma unroll
        for (int i = 0; i < 4; i++) af[i] = *(const bf16x8*)&As[(wm + i * 16 + r) * 32 + q * 8];
#pragma unroll
        for (int j = 0; j < 2; j++) {
            f1[j] = *(const bf16x8*)&B1s[(wn + j * 16 + r) * 32 + q * 8];
            f3[j] = *(const bf16x8*)&B3s[(wn + j * 16 + r) * 32 + q * 8];
        }
#pragma unroll
        for (int i = 0; i < 4; i++)
#pragma unroll
            for (int j = 0; j < 2; j++) {
                acc1[i][j] = mfma16(af[i], f1[j], acc1[i][j]);
                acc3[i][j] = mfma16(af[i], f3[j], acc3[i][j]);
            }
        __syncthreads();
    }
    float s1v[2], s3v[2];
#pragma unroll
    for (int j = 0; j < 2; j++) {
        int col = n0 + wn + j * 16 + r;
        s1v[j] = b1e[col]; s3v[j] = b3e[col];
    }
#pragma unroll
    for (int i = 0; i < 4; i++)
#pragma unroll
        for (int j = 0; j < 2; j++)
#pragma unroll
            for (int g = 0; g < 4; g++) {
                int slot = m0 + wm + i * 16 + q * 4 + g;
                int col = n0 + wn + j * 16 + r;
                float z1 = acc1[i][j][g] + s1v[j];
                float z3 = acc3[i][j][g] + s3v[j];
                float h = (z1 / (1.f + __expf(-z1))) * z3;
                Hr[(size_t)slot * DFF + col] = f2bf1(h);
            }
}

// ---------------- routed GEMM2 (128x128): out += gw*(Hr@w2^T + b2) ----------------
__global__ __launch_bounds__(256) void k_rgemm2(const u16t* __restrict__ Hr,
        const u16t* __restrict__ w2b, const float* __restrict__ b2,
        const int* __restrict__ stok, const float* __restrict__ swt,
        const int* __restrict__ texp, const int* __restrict__ tm0,
        float* __restrict__ out) {
    const int te = texp[blockIdx.x];
    if (te < 0) return;
    const int m0 = tm0[blockIdx.x], n0 = blockIdx.y * 128;
    __shared__ u16t As[128 * 32], Bs[128 * 32];
    __shared__ int toksR[128];
    __shared__ float swtL[128];
    const int tid = threadIdx.x, lane = tid & 63, wid = tid >> 6;
    const int wm = (wid & 1) * 64, wn = (wid >> 1) * 64;
    const int q = lane >> 4, r = lane & 15;
    const int srow = tid >> 2, scg = (tid & 3) * 8;
    if (tid < 128) { toksR[tid] = stok[m0 + tid]; swtL[tid] = swt[m0 + tid]; }
    floatx4 acc[4][4];
#pragma unroll
    for (int i = 0; i < 4; i++)
#pragma unroll
        for (int j = 0; j < 4; j++) acc[i][j] = (floatx4)0.f;
    const u16t* a0 = Hr + (size_t)(m0 + srow) * DFF + scg;
    const u16t* a1 = Hr + (size_t)(m0 + 64 + srow) * DFF + scg;
    const u16t* b0 = w2b + (size_t)te * DD * DFF + (size_t)(n0 + srow) * DFF + scg;
    const u16t* b1 = w2b + (size_t)te * DD * DFF + (size_t)(n0 + 64 + srow) * DFF + scg;
    const float* b2e = b2 + (size_t)te * DD;
    u16t* lA0 = As + tid * 8;       u16t* lA1 = As + 2048 + tid * 8;
    u16t* lB0 = Bs + tid * 8;       u16t* lB1 = Bs + 2048 + tid * 8;
    for (int k0 = 0; k0 < DFF; k0 += 32) {
        glds16(a0 + k0, lA0); glds16(a1 + k0, lA1);
        glds16(b0 + k0, lB0); glds16(b1 + k0, lB1);
        __syncthreads();
        bf16x8 af[4], bf[4];
#pragma unroll
        for (int i = 0; i < 4; i++) af[i] = *(const bf16x8*)&As[(wm + i * 16 + r) * 32 + q * 8];
#pragma unroll
        for (int j = 0; j < 4; j++) bf[j] = *(const bf16x8*)&Bs[(wn + j * 16 + r) * 32 + q * 8];
#pragma unroll
        for (int i = 0; i < 4; i++)
#pragma unroll
            for (int j = 0; j < 4; j++) acc[i][j] = mfma16(af[i], bf[j], acc[i][j]);
        __syncthreads();
    }
    float bv[4];
#pragma unroll
    for (int j = 0; j < 4; j++) bv[j] = b2e[n0 + wn + j * 16 + r];
#pragma unroll
    for (int i = 0; i < 4; i++)
#pragma unroll
        for (int g = 0; g < 4; g++) {
            int rowl = wm + i * 16 + q * 4 + g;
            int tk = toksR[rowl];
            if (tk >= 0) {
                float gwv = swtL[rowl];
#pragma unroll
                for (int j = 0; j < 4; j++) {
                    int col = n0 + wn + j * 16 + r;
                    atomicAdd(out + (size_t)tk * DD + col, gwv * (acc[i][j][g] + bv[j]));
                }
            }
        }
}

extern "C" void kernel_launch(void* const* d_in, const int* in_sizes, int n_in,
                              void* d_out, int out_size, void* d_ws, size_t ws_size,
                              hipStream_t stream) {
    const float* x   = (const float*)d_in[0];
    const float* gw  = (const float*)d_in[1];
    const float* eb  = (const float*)d_in[2];
    const float* w1  = (const float*)d_in[3];
    const float* b1  = (const float*)d_in[4];
    const float* w3  = (const float*)d_in[5];
    const float* b3  = (const float*)d_in[6];
    const float* w2  = (const float*)d_in[7];
    const float* b2  = (const float*)d_in[8];
    const float* sw1 = (const float*)d_in[9];
    const float* sb1 = (const float*)d_in[10];
    const float* sw3 = (const float*)d_in[11];
    const float* sb3 = (const float*)d_in[12];
    const float* sw2 = (const float*)d_in[13];
    const float* sb2 = (const float*)d_in[14];
    float* out = (float*)d_out;
    char* ws = (char*)d_ws;

    u16t*  xb   = (u16t*)(ws + XB_OFF);
    u16t*  Hs   = (u16t*)(ws + HS_OFF);
    u16t*  Hr   = (u16t*)(ws + HR_OFF);
    u16t*  w1b  = (u16t*)(ws + W1B_OFF);
    u16t*  w3b  = (u16t*)(ws + W3B_OFF);
    u16t*  w2b  = (u16t*)(ws + W2B_OFF);
    u16t*  sw1b = (u16t*)(ws + SW1B_OFF);
    u16t*  sw3b = (u16t*)(ws + SW3B_OFF);
    u16t*  sw2b = (u16t*)(ws + SW2B_OFF);
    int*   tki  = (int*)(ws + TKI_OFF);
    float* tkw  = (float*)(ws + TKW_OFF);
    int*   stok = (int*)(ws + STOK_OFF);
    float* swt  = (float*)(ws + SWT_OFF);
    int*   cnt  = (int*)(ws + CNT_OFF);
    int*   cur  = (int*)(ws + CUR_OFF);
    int*   offs = (int*)(ws + OFS_OFF);
    int*   texp = (int*)(ws + TEX_OFF);
    int*   tm0  = (int*)(ws + TM0_OFF);

    hipMemsetAsync(cnt, 0, 128, stream);
    hipMemsetAsync(stok, 0xFF, (size_t)NSLOT_PAD * 4, stream);

    k_cvtw<<<13824, 256, 0, stream>>>(w1, w3, w2, sw1, sw3, sw2, w1b, w3b, w2b, sw1b, sw3b, sw2b);
    k_cvtx<<<4096, 256, 0, stream>>>(x, xb);
    k_gate<<<512, 256, 0, stream>>>(x, gw, eb, tki, tkw, cnt);
    k_scan<<<1, 64, 0, stream>>>(cnt, offs, texp, tm0);
    k_scatter<<<NSLOT / 256, 256, 0, stream>>>(tki, tkw, offs, cur, stok, swt);

    k_sgemm1<<<dim3(TT / 128, FDFF / 64), 256, 0, stream>>>(xb, sw1b, sb1, sw3b, sb3, Hs);
    k_sgemm2<<<dim3(TT / 128, DD / 128), 256, 0, stream>>>(Hs, sw2b, sb2, out);
    k_rgemm1<<<dim3(MAXT, DFF / 64), 256, 0, stream>>>(xb, w1b, b1, w3b, b3, stok, texp, tm0, Hr);
    k_rgemm2<<<dim3(MAXT, DD / 128), 256, 0, stream>>>(Hr, w2b, b2, stok, swt, texp, tm0, out);
}

// Round 4
// 462.039 us; speedup vs baseline: 1.4855x; 1.4855x over previous
//
#include <hip/hip_runtime.h>
#include <cstdint>
#include <cstddef>

#define DEV static __device__ __forceinline__

constexpr int TT   = 8192;   // B*S tokens
constexpr int DD   = 1024;   // d_model
constexpr int DFF  = 512;
constexpr int NE   = 16;
constexpr int FDFF = 1024;   // fused shared dff
constexpr int NSLOT = TT * 2;                 // token-expert pairs
constexpr int NSLOT_PAD = NSLOT + NE * 128;   // padded to 128-row tiles
constexpr int MAXT = NSLOT / 128 + NE;        // 144 max live m-tiles
constexpr int HB   = 64;                      // hist blocks (256 entries each)

// ---- workspace layout (bytes) ----
constexpr size_t XB_OFF   = 0;                                    // x bf16 [T,D]
constexpr size_t HS_OFF   = XB_OFF  + (size_t)TT * DD * 2;        // shared hidden bf16 [T,FDFF]
constexpr size_t HR_OFF   = HS_OFF  + (size_t)TT * FDFF * 2;      // routed hidden bf16 [NSLOT_PAD,DFF]
constexpr size_t W1B_OFF  = HR_OFF  + (size_t)NSLOT_PAD * DFF * 2;
constexpr size_t W3B_OFF  = W1B_OFF + (size_t)NE * DFF * DD * 2;
constexpr size_t W2B_OFF  = W3B_OFF + (size_t)NE * DFF * DD * 2;
constexpr size_t SW1B_OFF = W2B_OFF + (size_t)NE * DD * DFF * 2;
constexpr size_t SW3B_OFF = SW1B_OFF + (size_t)FDFF * DD * 2;
constexpr size_t SW2B_OFF = SW3B_OFF + (size_t)FDFF * DD * 2;
constexpr size_t TKI_OFF  = SW2B_OFF + (size_t)DD * FDFF * 2;
constexpr size_t TKW_OFF  = TKI_OFF + (size_t)NSLOT * 4;
constexpr size_t STOK_OFF = TKW_OFF + (size_t)NSLOT * 4;
constexpr size_t SWT_OFF  = STOK_OFF + (size_t)NSLOT_PAD * 4;
constexpr size_t LRK_OFF  = SWT_OFF + (size_t)NSLOT_PAD * 4;      // local rank [NSLOT]
constexpr size_t BCN_OFF  = LRK_OFF + (size_t)NSLOT * 4;          // blockCnt [HB][16]
constexpr size_t BB_OFF   = BCN_OFF + (size_t)HB * NE * 4;        // blockBase [HB][16]
constexpr size_t OFS_OFF  = BB_OFF + (size_t)HB * NE * 4;         // offsets[17]
constexpr size_t TEX_OFF  = OFS_OFF + 128;                        // tile->expert
constexpr size_t TM0_OFF  = TEX_OFF + (size_t)MAXT * 4;           // tile->slot0

typedef __bf16 bf16x8 __attribute__((ext_vector_type(8)));
typedef float  floatx4 __attribute__((ext_vector_type(4)));
typedef unsigned short u16t;

DEV unsigned f2bf2(float lo, float hi) {
    unsigned a = __builtin_bit_cast(unsigned, lo);
    unsigned b = __builtin_bit_cast(unsigned, hi);
    a += 0x7FFFu + ((a >> 16) & 1u);
    b += 0x7FFFu + ((b >> 16) & 1u);
    return (a >> 16) | (b & 0xFFFF0000u);
}
DEV u16t f2bf1(float f) {
    unsigned u = __builtin_bit_cast(unsigned, f);
    u += 0x7FFFu + ((u >> 16) & 1u);
    return (u16t)(u >> 16);
}
DEV uint4 pack8(float4 a, float4 b) {
    uint4 r;
    r.x = f2bf2(a.x, a.y); r.y = f2bf2(a.z, a.w);
    r.z = f2bf2(b.x, b.y); r.w = f2bf2(b.z, b.w);
    return r;
}
DEV floatx4 mfma16(bf16x8 a, bf16x8 b, floatx4 c) {
    return __builtin_amdgcn_mfma_f32_16x16x32_bf16(a, b, c, 0, 0, 0);
}
DEV void glds16(const u16t* g, u16t* l) {   // async global->LDS, 16B/lane
    __builtin_amdgcn_global_load_lds(
        (const __attribute__((address_space(1))) unsigned int*)g,
        (__attribute__((address_space(3))) unsigned int*)l, 16, 0, 0);
}
DEV float dot4(float4 a, float4 b) { return a.x*b.x + a.y*b.y + a.z*b.z + a.w*b.w; }

// ---------------- weight fp32 -> bf16 pre-convert ----------------
__global__ __launch_bounds__(256) void k_cvtw(
        const float* __restrict__ w1, const float* __restrict__ w3, const float* __restrict__ w2,
        const float* __restrict__ sw1, const float* __restrict__ sw3, const float* __restrict__ sw2,
        u16t* __restrict__ w1b, u16t* __restrict__ w3b, u16t* __restrict__ w2b,
        u16t* __restrict__ sw1b, u16t* __restrict__ sw3b, u16t* __restrict__ sw2b) {
    int b = blockIdx.x;
    const float* src; u16t* dst; size_t base;
    if      (b < 4096)  { src = w1;  dst = w1b;  base = (size_t)b * 2048; }
    else if (b < 8192)  { src = w3;  dst = w3b;  base = (size_t)(b - 4096) * 2048; }
    else if (b < 12288) { src = w2;  dst = w2b;  base = (size_t)(b - 8192) * 2048; }
    else if (b < 12800) { src = sw1; dst = sw1b; base = (size_t)(b - 12288) * 2048; }
    else if (b < 13312) { src = sw3; dst = sw3b; base = (size_t)(b - 12800) * 2048; }
    else                { src = sw2; dst = sw2b; base = (size_t)(b - 13312) * 2048; }
    size_t i = base + (size_t)threadIdx.x * 8;
    float4 a = *(const float4*)(src + i);
    float4 c = *(const float4*)(src + i + 4);
    *(uint4*)(dst + i) = pack8(a, c);
}

// ---------------- x -> bf16 ----------------
__global__ __launch_bounds__(256) void k_cvtx(const float* __restrict__ x, u16t* __restrict__ xb) {
    size_t i = ((size_t)blockIdx.x * 256 + threadIdx.x) * 8;
    float4 a = *(const float4*)(x + i);
    float4 b = *(const float4*)(x + i + 4);
    *(uint4*)(xb + i) = pack8(a, b);
}

// ---------------- gate: top-2 only, NO global atomics ----------------
__global__ __launch_bounds__(256) void k_gate(const float* __restrict__ x,
                                              const float* __restrict__ gw,
                                              const float* __restrict__ eb,
                                              int* __restrict__ tki, float* __restrict__ tkw) {
    const int tid = threadIdx.x;
    const int wave = tid >> 6, lane = tid & 63;
    const int tok0 = blockIdx.x * 16 + wave * 4;
    float acc[4][16];
#pragma unroll
    for (int t = 0; t < 4; t++)
#pragma unroll
        for (int e = 0; e < 16; e++) acc[t][e] = 0.f;
#pragma unroll
    for (int i = 0; i < 4; i++) {
        const int d = i * 256 + lane * 4;
        float4 xv[4];
#pragma unroll
        for (int t = 0; t < 4; t++) xv[t] = *(const float4*)(x + (size_t)(tok0 + t) * DD + d);
#pragma unroll
        for (int e = 0; e < 16; e++) {
            float4 wv = *(const float4*)(gw + (size_t)e * DD + d);
#pragma unroll
            for (int t = 0; t < 4; t++) acc[t][e] += dot4(xv[t], wv);
        }
    }
#pragma unroll
    for (int t = 0; t < 4; t++)
#pragma unroll
        for (int e = 0; e < 16; e++) {
            float v = acc[t][e];
            v += __shfl_xor(v, 1);  v += __shfl_xor(v, 2);  v += __shfl_xor(v, 4);
            v += __shfl_xor(v, 8);  v += __shfl_xor(v, 16); v += __shfl_xor(v, 32);
            acc[t][e] = v;
        }
    if (lane == 0) {
        float ebs[16];
#pragma unroll
        for (int e = 0; e < 16; e++) ebs[e] = eb[e];
#pragma unroll
        for (int t = 0; t < 4; t++) {
            float b0 = -1e30f, b1v = -1e30f, l0 = 0.f, l1 = 0.f;
            int i0 = 0, i1 = 0;
#pragma unroll
            for (int e = 0; e < 16; e++) {
                float lv = acc[t][e];
                float bl = lv + ebs[e];
                if (bl > b0)       { b1v = b0; i1 = i0; l1 = l0; b0 = bl; i0 = e; l0 = lv; }
                else if (bl > b1v) { b1v = bl; i1 = e; l1 = lv; }
            }
            float s0 = 1.f / (1.f + expf(-l0));
            float s1 = 1.f / (1.f + expf(-l1));
            float dn = s0 + s1 + 1e-10f;
            int tok = tok0 + t;
            tki[tok * 2] = i0; tki[tok * 2 + 1] = i1;
            tkw[tok * 2] = s0 / dn; tkw[tok * 2 + 1] = s1 / dn;
        }
    }
}

// ---------------- hist: per-block LDS histogram + local ranks ----------------
__global__ __launch_bounds__(256) void k_hist(const int* __restrict__ tki,
                                              int* __restrict__ lrank, int* __restrict__ bcnt) {
    __shared__ int h[NE];
    const int tid = threadIdx.x;
    if (tid < NE) h[tid] = 0;
    __syncthreads();
    int idx = blockIdx.x * 256 + tid;
    int e = tki[idx];
    lrank[idx] = atomicAdd(&h[e], 1);   // LDS atomic -- no global contention
    __syncthreads();
    if (tid < NE) bcnt[blockIdx.x * NE + tid] = h[tid];
}

// ---------------- scan: expert offsets (128-padded), tile map, block bases ----------------
__global__ void k_scan(const int* __restrict__ bcnt, int* __restrict__ offs,
                       int* __restrict__ bb, int* __restrict__ texp, int* __restrict__ tm0) {
    __shared__ int cntS[NE], offS[NE];
    const int tid = threadIdx.x;
    if (tid < NE) {
        int s = 0;
#pragma unroll
        for (int b = 0; b < HB; b++) s += bcnt[b * NE + tid];
        cntS[tid] = s;
    }
    __syncthreads();
    if (tid == 0) {
        int off = 0, t = 0;
        for (int e = 0; e < NE; e++) {
            offS[e] = off; offs[e] = off;
            int nt = (cntS[e] + 127) >> 7;
            for (int i = 0; i < nt; i++) { texp[t] = e; tm0[t] = off + i * 128; t++; }
            off += nt * 128;
        }
        offs[NE] = off;
        for (; t < MAXT; t++) texp[t] = -1;
    }
    __syncthreads();
    if (tid < NE) {
        int run = offS[tid];
        for (int b = 0; b < HB; b++) { bb[b * NE + tid] = run; run += bcnt[b * NE + tid]; }
    }
}

// ---------------- scatter: pure gather/store, zero atomics ----------------
__global__ __launch_bounds__(256) void k_scatter(const int* __restrict__ tki,
                                                 const float* __restrict__ tkw,
                                                 const int* __restrict__ bb,
                                                 const int* __restrict__ lrank,
                                                 int* __restrict__ stok, float* __restrict__ swt) {
    int idx = blockIdx.x * 256 + threadIdx.x;
    int e = tki[idx];
    int slot = bb[blockIdx.x * NE + e] + lrank[idx];
    stok[slot] = idx >> 1;
    swt[slot] = tkw[idx];
}

// ---------------- shared GEMM1 (dual 128x64): Hs = swiglu ----------------
__global__ __launch_bounds__(256) void k_sgemm1(const u16t* __restrict__ xb,
        const u16t* __restrict__ w1b, const float* __restrict__ sb1,
        const u16t* __restrict__ w3b, const float* __restrict__ sb3,
        u16t* __restrict__ Hs) {
    __shared__ u16t As[128 * 32], B1s[64 * 32], B3s[64 * 32];
    const int m0 = blockIdx.x * 128, n0 = blockIdx.y * 64;
    const int tid = threadIdx.x, lane = tid & 63, wid = tid >> 6;
    const int wm = (wid & 1) * 64, wn = (wid >> 1) * 32;
    const int q = lane >> 4, r = lane & 15;
    const int srow = tid >> 2, scg = (tid & 3) * 8;
    floatx4 acc1[4][2], acc3[4][2];
#pragma unroll
    for (int i = 0; i < 4; i++)
#pragma unroll
        for (int j = 0; j < 2; j++) { acc1[i][j] = (floatx4)0.f; acc3[i][j] = (floatx4)0.f; }
    const u16t* a0  = xb  + (size_t)(m0 + srow) * DD + scg;
    const u16t* a1  = xb  + (size_t)(m0 + 64 + srow) * DD + scg;
    const u16t* b1g = w1b + (size_t)(n0 + srow) * DD + scg;
    const u16t* b3g = w3b + (size_t)(n0 + srow) * DD + scg;
    u16t* lA0 = As + tid * 8;
    u16t* lA1 = As + 2048 + tid * 8;
    u16t* lB1 = B1s + tid * 8;
    u16t* lB3 = B3s + tid * 8;
    for (int k0 = 0; k0 < DD; k0 += 32) {
        glds16(a0 + k0, lA0); glds16(a1 + k0, lA1);
        glds16(b1g + k0, lB1); glds16(b3g + k0, lB3);
        __syncthreads();
        bf16x8 af[4], f1[2], f3[2];
#pragma unroll
        for (int i = 0; i < 4; i++) af[i] = *(const bf16x8*)&As[(wm + i * 16 + r) * 32 + q * 8];
#pragma unroll
        for (int j = 0; j < 2; j++) {
            f1[j] = *(const bf16x8*)&B1s[(wn + j * 16 + r) * 32 + q * 8];
            f3[j] = *(const bf16x8*)&B3s[(wn + j * 16 + r) * 32 + q * 8];
        }
#pragma unroll
        for (int i = 0; i < 4; i++)
#pragma unroll
            for (int j = 0; j < 2; j++) {
                acc1[i][j] = mfma16(af[i], f1[j], acc1[i][j]);
                acc3[i][j] = mfma16(af[i], f3[j], acc3[i][j]);
            }
        __syncthreads();
    }
    float s1v[2], s3v[2];
#pragma unroll
    for (int j = 0; j < 2; j++) {
        int col = n0 + wn + j * 16 + r;
        s1v[j] = sb1[col]; s3v[j] = sb3[col];
    }
#pragma unroll
    for (int i = 0; i < 4; i++)
#pragma unroll
        for (int j = 0; j < 2; j++)
#pragma unroll
            for (int g = 0; g < 4; g++) {
                int row = m0 + wm + i * 16 + q * 4 + g;
                int col = n0 + wn + j * 16 + r;
                float z1 = acc1[i][j][g] + s1v[j];
                float z3 = acc3[i][j][g] + s3v[j];
                float h = (z1 / (1.f + __expf(-z1))) * z3;
                Hs[(size_t)row * FDFF + col] = f2bf1(h);
            }
}

// ---------------- shared GEMM2 (128x128): out = Hs@sw2^T + sb2 ----------------
__global__ __launch_bounds__(256) void k_sgemm2(const u16t* __restrict__ Hs,
        const u16t* __restrict__ sw2b, const float* __restrict__ sb2,
        float* __restrict__ out) {
    __shared__ u16t As[128 * 32], Bs[128 * 32];
    const int m0 = blockIdx.x * 128, n0 = blockIdx.y * 128;
    const int tid = threadIdx.x, lane = tid & 63, wid = tid >> 6;
    const int wm = (wid & 1) * 64, wn = (wid >> 1) * 64;
    const int q = lane >> 4, r = lane & 15;
    const int srow = tid >> 2, scg = (tid & 3) * 8;
    floatx4 acc[4][4];
#pragma unroll
    for (int i = 0; i < 4; i++)
#pragma unroll
        for (int j = 0; j < 4; j++) acc[i][j] = (floatx4)0.f;
    const u16t* a0 = Hs + (size_t)(m0 + srow) * FDFF + scg;
    const u16t* a1 = Hs + (size_t)(m0 + 64 + srow) * FDFF + scg;
    const u16t* b0 = sw2b + (size_t)(n0 + srow) * FDFF + scg;
    const u16t* b1 = sw2b + (size_t)(n0 + 64 + srow) * FDFF + scg;
    u16t* lA0 = As + tid * 8;       u16t* lA1 = As + 2048 + tid * 8;
    u16t* lB0 = Bs + tid * 8;       u16t* lB1 = Bs + 2048 + tid * 8;
    for (int k0 = 0; k0 < FDFF; k0 += 32) {
        glds16(a0 + k0, lA0); glds16(a1 + k0, lA1);
        glds16(b0 + k0, lB0); glds16(b1 + k0, lB1);
        __syncthreads();
        bf16x8 af[4], bf[4];
#pragma unroll
        for (int i = 0; i < 4; i++) af[i] = *(const bf16x8*)&As[(wm + i * 16 + r) * 32 + q * 8];
#pragma unroll
        for (int j = 0; j < 4; j++) bf[j] = *(const bf16x8*)&Bs[(wn + j * 16 + r) * 32 + q * 8];
#pragma unroll
        for (int i = 0; i < 4; i++)
#pragma unroll
            for (int j = 0; j < 4; j++) acc[i][j] = mfma16(af[i], bf[j], acc[i][j]);
        __syncthreads();
    }
    float bv[4];
#pragma unroll
    for (int j = 0; j < 4; j++) bv[j] = sb2[n0 + wn + j * 16 + r];
#pragma unroll
    for (int i = 0; i < 4; i++)
#pragma unroll
        for (int j = 0; j < 4; j++)
#pragma unroll
            for (int g = 0; g < 4; g++) {
                int row = m0 + wm + i * 16 + q * 4 + g;
                int col = n0 + wn + j * 16 + r;
                out[(size_t)row * DD + col] = acc[i][j][g] + bv[j];
            }
}

// ---------------- routed GEMM1 (dual 128x64, gathered) ----------------
__global__ __launch_bounds__(256) void k_rgemm1(const u16t* __restrict__ xb,
        const u16t* __restrict__ w1b, const float* __restrict__ b1,
        const u16t* __restrict__ w3b, const float* __restrict__ b3,
        const int* __restrict__ stok,
        const int* __restrict__ texp, const int* __restrict__ tm0,
        u16t* __restrict__ Hr) {
    const int te = texp[blockIdx.x];
    if (te < 0) return;
    const int m0 = tm0[blockIdx.x], n0 = blockIdx.y * 64;
    __shared__ u16t As[128 * 32], B1s[64 * 32], B3s[64 * 32];
    __shared__ int toksS[128];
    const int tid = threadIdx.x, lane = tid & 63, wid = tid >> 6;
    const int wm = (wid & 1) * 64, wn = (wid >> 1) * 32;
    const int q = lane >> 4, r = lane & 15;
    const int srow = tid >> 2, scg = (tid & 3) * 8;
    if (tid < 128) { int t = stok[m0 + tid]; toksS[tid] = t < 0 ? 0 : t; }
    __syncthreads();
    floatx4 acc1[4][2], acc3[4][2];
#pragma unroll
    for (int i = 0; i < 4; i++)
#pragma unroll
        for (int j = 0; j < 2; j++) { acc1[i][j] = (floatx4)0.f; acc3[i][j] = (floatx4)0.f; }
    const u16t* a0  = xb + (size_t)toksS[srow] * DD + scg;
    const u16t* a1  = xb + (size_t)toksS[64 + srow] * DD + scg;
    const u16t* b1g = w1b + (size_t)te * DFF * DD + (size_t)(n0 + srow) * DD + scg;
    const u16t* b3g = w3b + (size_t)te * DFF * DD + (size_t)(n0 + srow) * DD + scg;
    const float* b1e = b1 + (size_t)te * DFF;
    const float* b3e = b3 + (size_t)te * DFF;
    u16t* lA0 = As + tid * 8;
    u16t* lA1 = As + 2048 + tid * 8;
    u16t* lB1 = B1s + tid * 8;
    u16t* lB3 = B3s + tid * 8;
    for (int k0 = 0; k0 < DD; k0 += 32) {
        glds16(a0 + k0, lA0); glds16(a1 + k0, lA1);
        glds16(b1g + k0, lB1); glds16(b3g + k0, lB3);
        __syncthreads();
        bf16x8 af[4], f1[2], f3[2];
#pragma unroll
        for (int i = 0; i < 4; i++) af[i] = *(const bf16x8*)&As[(wm + i * 16 + r) * 32 + q * 8];
#pragma unroll
        for (int j = 0; j < 2; j++) {
            f1[j] = *(const bf16x8*)&B1s[(wn + j * 16 + r) * 32 + q * 8];
            f3[j] = *(const bf16x8*)&B3s[(wn + j * 16 + r) * 32 + q * 8];
        }
#pragma unroll
        for (int i = 0; i < 4; i++)
#pragma unroll
            for (int j = 0; j < 2; j++) {
                acc1[i][j] = mfma16(af[i], f1[j], acc1[i][j]);
                acc3[i][j] = mfma16(af[i], f3[j], acc3[i][j]);
            }
        __syncthreads();
    }
    float s1v[2], s3v[2];
#pragma unroll
    for (int j = 0; j < 2; j++) {
        int col = n0 + wn + j * 16 + r;
        s1v[j] = b1e[col]; s3v[j] = b3e[col];
    }
#pragma unroll
    for (int i = 0; i < 4; i++)
#pragma unroll
        for (int j = 0; j < 2; j++)
#pragma unroll
            for (int g = 0; g < 4; g++) {
                int slot = m0 + wm + i * 16 + q * 4 + g;
                int col = n0 + wn + j * 16 + r;
                float z1 = acc1[i][j][g] + s1v[j];
                float z3 = acc3[i][j][g] + s3v[j];
                float h = (z1 / (1.f + __expf(-z1))) * z3;
                Hr[(size_t)slot * DFF + col] = f2bf1(h);
            }
}

// ---------------- routed GEMM2 (128x128): out += gw*(Hr@w2^T + b2)  (atomic, distinct addrs) ----------------
__global__ __launch_bounds__(256) void k_rgemm2(const u16t* __restrict__ Hr,
        const u16t* __restrict__ w2b, const float* __restrict__ b2,
        const int* __restrict__ stok, const float* __restrict__ swt,
        const int* __restrict__ texp, const int* __restrict__ tm0,
        float* __restrict__ out) {
    const int te = texp[blockIdx.x];
    if (te < 0) return;
    const int m0 = tm0[blockIdx.x], n0 = blockIdx.y * 128;
    __shared__ u16t As[128 * 32], Bs[128 * 32];
    __shared__ int toksR[128];
    __shared__ float swtL[128];
    const int tid = threadIdx.x, lane = tid & 63, wid = tid >> 6;
    const int wm = (wid & 1) * 64, wn = (wid >> 1) * 64;
    const int q = lane >> 4, r = lane & 15;
    const int srow = tid >> 2, scg = (tid & 3) * 8;
    if (tid < 128) { toksR[tid] = stok[m0 + tid]; swtL[tid] = swt[m0 + tid]; }
    floatx4 acc[4][4];
#pragma unroll
    for (int i = 0; i < 4; i++)
#pragma unroll
        for (int j = 0; j < 4; j++) acc[i][j] = (floatx4)0.f;
    const u16t* a0 = Hr + (size_t)(m0 + srow) * DFF + scg;
    const u16t* a1 = Hr + (size_t)(m0 + 64 + srow) * DFF + scg;
    const u16t* b0 = w2b + (size_t)te * DD * DFF + (size_t)(n0 + srow) * DFF + scg;
    const u16t* b1 = w2b + (size_t)te * DD * DFF + (size_t)(n0 + 64 + srow) * DFF + scg;
    const float* b2e = b2 + (size_t)te * DD;
    u16t* lA0 = As + tid * 8;       u16t* lA1 = As + 2048 + tid * 8;
    u16t* lB0 = Bs + tid * 8;       u16t* lB1 = Bs + 2048 + tid * 8;
    for (int k0 = 0; k0 < DFF; k0 += 32) {
        glds16(a0 + k0, lA0); glds16(a1 + k0, lA1);
        glds16(b0 + k0, lB0); glds16(b1 + k0, lB1);
        __syncthreads();
        bf16x8 af[4], bf[4];
#pragma unroll
        for (int i = 0; i < 4; i++) af[i] = *(const bf16x8*)&As[(wm + i * 16 + r) * 32 + q * 8];
#pragma unroll
        for (int j = 0; j < 4; j++) bf[j] = *(const bf16x8*)&Bs[(wn + j * 16 + r) * 32 + q * 8];
#pragma unroll
        for (int i = 0; i < 4; i++)
#pragma unroll
            for (int j = 0; j < 4; j++) acc[i][j] = mfma16(af[i], bf[j], acc[i][j]);
        __syncthreads();
    }
    float bv[4];
#pragma unroll
    for (int j = 0; j < 4; j++) bv[j] = b2e[n0 + wn + j * 16 + r];
#pragma unroll
    for (int i = 0; i < 4; i++)
#pragma unroll
        for (int g = 0; g < 4; g++) {
            int rowl = wm + i * 16 + q * 4 + g;
            int tk = toksR[rowl];
            if (tk >= 0) {
                float gwv = swtL[rowl];
#pragma unroll
                for (int j = 0; j < 4; j++) {
                    int col = n0 + wn + j * 16 + r;
                    atomicAdd(out + (size_t)tk * DD + col, gwv * (acc[i][j][g] + bv[j]));
                }
            }
        }
}

extern "C" void kernel_launch(void* const* d_in, const int* in_sizes, int n_in,
                              void* d_out, int out_size, void* d_ws, size_t ws_size,
                              hipStream_t stream) {
    const float* x   = (const float*)d_in[0];
    const float* gw  = (const float*)d_in[1];
    const float* eb  = (const float*)d_in[2];
    const float* w1  = (const float*)d_in[3];
    const float* b1  = (const float*)d_in[4];
    const float* w3  = (const float*)d_in[5];
    const float* b3  = (const float*)d_in[6];
    const float* w2  = (const float*)d_in[7];
    const float* b2  = (const float*)d_in[8];
    const float* sw1 = (const float*)d_in[9];
    const float* sb1 = (const float*)d_in[10];
    const float* sw3 = (const float*)d_in[11];
    const float* sb3 = (const float*)d_in[12];
    const float* sw2 = (const float*)d_in[13];
    const float* sb2 = (const float*)d_in[14];
    float* out = (float*)d_out;
    char* ws = (char*)d_ws;

    u16t*  xb   = (u16t*)(ws + XB_OFF);
    u16t*  Hs   = (u16t*)(ws + HS_OFF);
    u16t*  Hr   = (u16t*)(ws + HR_OFF);
    u16t*  w1b  = (u16t*)(ws + W1B_OFF);
    u16t*  w3b  = (u16t*)(ws + W3B_OFF);
    u16t*  w2b  = (u16t*)(ws + W2B_OFF);
    u16t*  sw1b = (u16t*)(ws + SW1B_OFF);
    u16t*  sw3b = (u16t*)(ws + SW3B_OFF);
    u16t*  sw2b = (u16t*)(ws + SW2B_OFF);
    int*   tki  = (int*)(ws + TKI_OFF);
    float* tkw  = (float*)(ws + TKW_OFF);
    int*   stok = (int*)(ws + STOK_OFF);
    float* swt  = (float*)(ws + SWT_OFF);
    int*   lrank = (int*)(ws + LRK_OFF);
    int*   bcnt = (int*)(ws + BCN_OFF);
    int*   bb   = (int*)(ws + BB_OFF);
    int*   offs = (int*)(ws + OFS_OFF);
    int*   texp = (int*)(ws + TEX_OFF);
    int*   tm0  = (int*)(ws + TM0_OFF);

    hipMemsetAsync(stok, 0xFF, (size_t)NSLOT_PAD * 4, stream);  // pad slots = -1

    k_cvtw<<<13824, 256, 0, stream>>>(w1, w3, w2, sw1, sw3, sw2, w1b, w3b, w2b, sw1b, sw3b, sw2b);
    k_cvtx<<<4096, 256, 0, stream>>>(x, xb);
    k_gate<<<512, 256, 0, stream>>>(x, gw, eb, tki, tkw);
    k_hist<<<HB, 256, 0, stream>>>(tki, lrank, bcnt);
    k_scan<<<1, 64, 0, stream>>>(bcnt, offs, bb, texp, tm0);
    k_scatter<<<HB, 256, 0, stream>>>(tki, tkw, bb, lrank, stok, swt);

    k_sgemm1<<<dim3(TT / 128, FDFF / 64), 256, 0, stream>>>(xb, sw1b, sb1, sw3b, sb3, Hs);
    k_sgemm2<<<dim3(TT / 128, DD / 128), 256, 0, stream>>>(Hs, sw2b, sb2, out);
    k_rgemm1<<<dim3(MAXT, DFF / 64), 256, 0, stream>>>(xb, w1b, b1, w3b, b3, stok, texp, tm0, Hr);
    k_rgemm2<<<dim3(MAXT, DD / 128), 256, 0, stream>>>(Hr, w2b, b2, stok, swt, texp, tm0, out);
}